// Round 1
// baseline (266.793 us; speedup 1.0000x reference)
//
#include <hip/hip_runtime.h>
#include <math.h>

#define NTOK 32768
#define KCB  1024
#define DIM  64

// ---- workspace layout (float offsets) ----
#define WS_XR      0                       // [NTOK*64] rotated vectors
#define WS_ENORM   2097152                 // [1024] ||e_k||^2
#define WS_COUNTS  (WS_ENORM + 1024)       // [1024]
#define WS_CS      (WS_COUNTS + 1024)      // [1024] smoothed cluster size
#define WS_XRSUM   (WS_CS + 1024)          // [64]   sum_n xr[n][d]
#define WS_ESUM    (WS_XRSUM + 64)         // [64]   sum_k c_k*emb[k][d]
#define WS_SCAL    (WS_ESUM + 64)          // [16]: 0=sq_sum 1=xrnorm_sum 2=c*||emb||^2 sum
#define WS_DW      (WS_SCAL + 16)          // [1024*64]
#define WS_PMIN    (WS_DW + 65536)         // [2*NTOK] partial min per k-half
#define WS_PIDX    (WS_PMIN + 65536)       // [2*NTOK] (int)
#define WS_IDX     (WS_PIDX + 65536)       // [NTOK]   (int)

// ---- output layout (float offsets) ----
#define O_Q    0
#define O_CB   2097152
#define O_CM   2097153
#define O_DV   2097154
#define O_PP   2097155
#define O_IDX  2097156
#define O_CS   2129924
#define O_EW   2130948
#define O_EMB  2196484

// ---------------------------------------------------------------------------
// 1) rotate: xr = xf @ H  (xf is x transposed to channel-last), plus
//    xr_sum[d] = sum_n xr[n][d]  and  scal[1] = sum_n ||xr_n||^2
__global__ __launch_bounds__(256) void k_rotate(const float* __restrict__ x,
    const float* __restrict__ rot, float* __restrict__ xr,
    float* __restrict__ xr_sum, float* __restrict__ scal)
{
    __shared__ float4 Hs[1024];   // H[j][d] as float4 over d
    __shared__ float  xs[64];
    __shared__ float  wred[4];
    int tid = threadIdx.x;
    const float4* rot4 = (const float4*)rot;
    for (int i = tid; i < 1024; i += 256) Hs[i] = rot4[i];
    if (tid < 64) xs[tid] = 0.f;
    __syncthreads();

    int n = blockIdx.x * 256 + tid;
    const float* xp = x + ((size_t)(n >> 10) << 16) + (n & 1023);
    float acc[64];
    #pragma unroll
    for (int d = 0; d < 64; ++d) acc[d] = 0.f;
    for (int j = 0; j < 64; ++j) {
        float xv = xp[(size_t)j << 10];
        #pragma unroll
        for (int q = 0; q < 16; ++q) {
            float4 h = Hs[(j << 4) + q];
            acc[4*q+0] = fmaf(xv, h.x, acc[4*q+0]);
            acc[4*q+1] = fmaf(xv, h.y, acc[4*q+1]);
            acc[4*q+2] = fmaf(xv, h.z, acc[4*q+2]);
            acc[4*q+3] = fmaf(xv, h.w, acc[4*q+3]);
        }
    }
    float4* xro = (float4*)(xr + ((size_t)n << 6));
    float nrm = 0.f;
    #pragma unroll
    for (int q = 0; q < 16; ++q) {
        float4 v = make_float4(acc[4*q], acc[4*q+1], acc[4*q+2], acc[4*q+3]);
        xro[q] = v;
        nrm += v.x*v.x + v.y*v.y + v.z*v.z + v.w*v.w;
    }
    #pragma unroll
    for (int d = 0; d < 64; ++d) {
        float v = acc[d];
        #pragma unroll
        for (int m = 32; m >= 1; m >>= 1) v += __shfl_xor(v, m);
        if ((tid & 63) == 0) atomicAdd(&xs[d], v);
    }
    #pragma unroll
    for (int m = 32; m >= 1; m >>= 1) nrm += __shfl_xor(nrm, m);
    if ((tid & 63) == 0) wred[tid >> 6] = nrm;
    __syncthreads();
    if (tid < 64) atomicAdd(&xr_sum[tid], xs[tid]);
    if (tid == 0) atomicAdd(&scal[1], wred[0] + wred[1] + wred[2] + wred[3]);
}

// ---------------------------------------------------------------------------
// 2) codebook norms
__global__ __launch_bounds__(256) void k_enorm(const float* __restrict__ E,
                                               float* __restrict__ enorm)
{
    int k = blockIdx.x * 256 + threadIdx.x;
    const float4* e4 = (const float4*)(E + ((size_t)k << 6));
    float s = 0.f;
    #pragma unroll
    for (int q = 0; q < 16; ++q) {
        float4 v = e4[q];
        s += v.x*v.x + v.y*v.y + v.z*v.z + v.w*v.w;
    }
    enorm[k] = s;
}

// ---------------------------------------------------------------------------
// 3) fused distance GEMM + argmin.
//    grid = 256 n-tiles x 2 k-halves. block 256 = 16(tx,k) x 16(ty,n).
//    Per-thread 8x8 register tile; LDS holds transposed xr[64][128] and
//    e[64][128] tiles (stride 132 -> conflict-free b128 reads).
#define LDT 132
__global__ __launch_bounds__(256) void k_argmin(const float* __restrict__ xr,
    const float* __restrict__ E, const float* __restrict__ enorm,
    float* __restrict__ pmin, int* __restrict__ pidx)
{
    __shared__ float xs[64 * LDT];
    __shared__ float es[64 * LDT];
    int tid = threadIdx.x;
    int tx = tid & 15, ty = tid >> 4;
    int nb = blockIdx.x >> 1;
    int kh = blockIdx.x & 1;
    int n0 = nb << 7;

    {   // stage xr tile transposed
        const float4* src = (const float4*)(xr + ((size_t)n0 << 6));
        #pragma unroll
        for (int it = 0; it < 8; ++it) {
            int q = tid + (it << 8);
            int row = q >> 4, d4 = (q & 15) << 2;
            float4 v = src[q];
            xs[(d4+0)*LDT + row] = v.x;
            xs[(d4+1)*LDT + row] = v.y;
            xs[(d4+2)*LDT + row] = v.z;
            xs[(d4+3)*LDT + row] = v.w;
        }
    }

    float best[8]; int bidx[8];
    #pragma unroll
    for (int i = 0; i < 8; ++i) { best[i] = 3.4e38f; bidx[i] = 0; }

    for (int kc = 0; kc < 4; ++kc) {
        int kbase = (kh << 9) + (kc << 7);
        __syncthreads();   // protect es (and xs on first iter) before overwrite/use
        {
            const float4* src = (const float4*)(E + ((size_t)kbase << 6));
            #pragma unroll
            for (int it = 0; it < 8; ++it) {
                int q = tid + (it << 8);
                int row = q >> 4, d4 = (q & 15) << 2;
                float4 v = src[q];
                es[(d4+0)*LDT + row] = v.x;
                es[(d4+1)*LDT + row] = v.y;
                es[(d4+2)*LDT + row] = v.z;
                es[(d4+3)*LDT + row] = v.w;
            }
        }
        __syncthreads();

        float acc[8][8];
        #pragma unroll
        for (int i = 0; i < 8; ++i)
            #pragma unroll
            for (int j = 0; j < 8; ++j) acc[i][j] = 0.f;

        int i0 = ty << 3, j0 = tx << 3;
        #pragma unroll 8
        for (int d = 0; d < 64; ++d) {
            const float* xa = &xs[d * LDT + i0];
            const float* eb = &es[d * LDT + j0];
            float4 a0 = *(const float4*)xa;
            float4 a1 = *(const float4*)(xa + 4);
            float4 b0 = *(const float4*)eb;
            float4 b1 = *(const float4*)(eb + 4);
            float a[8] = {a0.x,a0.y,a0.z,a0.w,a1.x,a1.y,a1.z,a1.w};
            float b[8] = {b0.x,b0.y,b0.z,b0.w,b1.x,b1.y,b1.z,b1.w};
            #pragma unroll
            for (int i = 0; i < 8; ++i)
                #pragma unroll
                for (int j = 0; j < 8; ++j)
                    acc[i][j] = fmaf(a[i], b[j], acc[i][j]);
        }

        // fold: s = ||e||^2 - 2*dot  (||xr||^2 omitted; constant per row)
        #pragma unroll
        for (int j = 0; j < 8; ++j) {
            int k = kbase + j0 + j;
            float en = enorm[k];
            #pragma unroll
            for (int i = 0; i < 8; ++i) {
                float s = fmaf(-2.f, acc[i][j], en);
                if (s < best[i]) { best[i] = s; bidx[i] = k; }
            }
        }
    }

    // reduce across the 16 tx lanes (contiguous lane group within wave)
    #pragma unroll
    for (int i = 0; i < 8; ++i) {
        float v = best[i]; int id = bidx[i];
        #pragma unroll
        for (int m = 8; m >= 1; m >>= 1) {
            float v2 = __shfl_xor(v, m);
            int id2 = __shfl_xor(id, m);
            if (v2 < v || (v2 == v && id2 < id)) { v = v2; id = id2; }
        }
        if (tx == 0) {
            int r = n0 + (ty << 3) + i;
            pmin[(kh << 15) + r] = v;
            pidx[(kh << 15) + r] = id;
        }
    }
}

// ---------------------------------------------------------------------------
// 4) merge k-halves, emit idx (ws + out), counts
__global__ __launch_bounds__(256) void k_merge(const float* __restrict__ pmin,
    const int* __restrict__ pidx, int* __restrict__ idxw,
    float* __restrict__ out_idx, float* __restrict__ counts)
{
    int n = blockIdx.x * 256 + threadIdx.x;
    float v0 = pmin[n];          int i0 = pidx[n];
    float v1 = pmin[32768 + n];  int i1 = pidx[32768 + n];
    int k = (v1 < v0 || (v1 == v0 && i1 < i0)) ? i1 : i0;
    idxw[n] = k;
    out_idx[n] = (float)k;
    atomicAdd(&counts[k], 1.0f);
}

// ---------------------------------------------------------------------------
// 5) quant output, squared-error sum, dw scatter
__global__ __launch_bounds__(256) void k_quant(const float* __restrict__ x,
    const float* __restrict__ E, const float* __restrict__ xr,
    const int* __restrict__ idxw, float* __restrict__ outq,
    float* __restrict__ dw, float* __restrict__ scal)
{
    int j = blockIdx.x * 256 + threadIdx.x;
    int n = j >> 6, d = j & 63;
    int k = idxw[n];
    float xv = x[j];
    float qa = E[(k << 6) + d];
    float dd = qa - xv;
    outq[j] = xv + dd;                 // x + (q - x), matches straight-through
    atomicAdd(&dw[(k << 6) + d], xr[j]);
    float sq = dd * dd;
    #pragma unroll
    for (int m = 32; m >= 1; m >>= 1) sq += __shfl_xor(sq, m);
    __shared__ float wr[4];
    if ((threadIdx.x & 63) == 0) wr[threadIdx.x >> 6] = sq;
    __syncthreads();
    if (threadIdx.x == 0) atomicAdd(&scal[0], wr[0] + wr[1] + wr[2] + wr[3]);
}

// ---------------------------------------------------------------------------
// 6) EMA cluster size + Laplace smoothing (single block, K=1024)
__global__ __launch_bounds__(1024) void k_ema(const float* __restrict__ ecs,
    const float* __restrict__ counts, float* __restrict__ out_cs,
    float* __restrict__ csw)
{
    int k = threadIdx.x;
    float cs = ecs[k] * 0.99f + 0.01f * counts[k];
    float v = cs;
    #pragma unroll
    for (int m = 32; m >= 1; m >>= 1) v += __shfl_xor(v, m);
    __shared__ float wr[16];
    __shared__ float ns;
    if ((k & 63) == 0) wr[k >> 6] = v;
    __syncthreads();
    if (k == 0) {
        float s = 0.f;
        for (int i = 0; i < 16; ++i) s += wr[i];
        ns = s;
    }
    __syncthreads();
    float nn = ns;
    float csf = (cs + 1e-5f) / (nn + 1024.f * 1e-5f) * nn;
    out_cs[k] = csf;
    csw[k] = csf;
}

// ---------------------------------------------------------------------------
// 7) new_ema_w, new_embedding, diversity partials
__global__ __launch_bounds__(256) void k_emb(const float* __restrict__ emaw,
    const float* __restrict__ dw, const float* __restrict__ csw,
    const float* __restrict__ counts, float* __restrict__ out_ew,
    float* __restrict__ out_emb, float* __restrict__ e_sum,
    float* __restrict__ scal)
{
    __shared__ float esl[64];
    __shared__ float wr[4];
    int tid = threadIdx.x;
    if (tid < 64) esl[tid] = 0.f;
    __syncthreads();
    int i = blockIdx.x * 256 + tid;
    int k = i >> 6, d = i & 63;
    float nw = emaw[i] * 0.99f + 0.01f * dw[i];
    out_ew[i] = nw;
    float emb = nw / csw[k];
    out_emb[i] = emb;
    float c = counts[k];
    atomicAdd(&esl[d], c * emb);
    float t = c * emb * emb;
    #pragma unroll
    for (int m = 32; m >= 1; m >>= 1) t += __shfl_xor(t, m);
    if ((tid & 63) == 0) wr[tid >> 6] = t;
    __syncthreads();
    if (tid < 64) atomicAdd(&e_sum[tid], esl[tid]);
    if (tid == 0) atomicAdd(&scal[2], wr[0] + wr[1] + wr[2] + wr[3]);
}

// ---------------------------------------------------------------------------
// 8) finalize scalars: losses, diversity, perplexity
__global__ __launch_bounds__(1024) void k_final(const float* __restrict__ counts,
    const float* __restrict__ scal, const float* __restrict__ xr_sum,
    const float* __restrict__ e_sum, float* __restrict__ out)
{
    int tid = threadIdx.x;
    float a = counts[tid] * (1.f / 32768.f);
    float t = a * logf(a + 1e-10f);
    float dc = (tid < 64) ? e_sum[tid] * xr_sum[tid] : 0.f;
    #pragma unroll
    for (int m = 32; m >= 1; m >>= 1) { t += __shfl_xor(t, m); dc += __shfl_xor(dc, m); }
    __shared__ float wt[16], wd[16];
    if ((tid & 63) == 0) { wt[tid >> 6] = t; wd[tid >> 6] = dc; }
    __syncthreads();
    if (tid == 0) {
        float S = 0.f, Dt = 0.f;
        for (int i = 0; i < 16; ++i) { S += wt[i]; Dt += wd[i]; }
        float cb = scal[0] * (1.f / 2097152.f);
        out[O_CB] = cb;
        out[O_CM] = 0.25f * cb;
        float inv = 1.f / 32768.f;
        out[O_DV] = scal[2] * inv + scal[1] * inv - 2.f * (Dt * inv * inv);
        out[O_PP] = expf(-S);
    }
}

// ---------------------------------------------------------------------------
extern "C" void kernel_launch(void* const* d_in, const int* in_sizes, int n_in,
                              void* d_out, int out_size, void* d_ws, size_t ws_size,
                              hipStream_t stream)
{
    const float* x    = (const float*)d_in[0];
    const float* E    = (const float*)d_in[1];
    const float* rot  = (const float*)d_in[2];
    const float* emaw = (const float*)d_in[3];
    const float* ecs  = (const float*)d_in[4];
    float* out = (float*)d_out;
    float* ws  = (float*)d_ws;

    // zero accumulators: counts..dw  (cs region included, overwritten anyway)
    hipMemsetAsync((void*)(ws + WS_COUNTS), 0,
                   (size_t)(WS_PMIN - WS_COUNTS) * sizeof(float), stream);

    hipLaunchKernelGGL(k_rotate, dim3(128), dim3(256), 0, stream,
                       x, rot, ws + WS_XR, ws + WS_XRSUM, ws + WS_SCAL);
    hipLaunchKernelGGL(k_enorm, dim3(4), dim3(256), 0, stream,
                       E, ws + WS_ENORM);
    hipLaunchKernelGGL(k_argmin, dim3(512), dim3(256), 0, stream,
                       ws + WS_XR, E, ws + WS_ENORM,
                       ws + WS_PMIN, (int*)(ws + WS_PIDX));
    hipLaunchKernelGGL(k_merge, dim3(128), dim3(256), 0, stream,
                       ws + WS_PMIN, (const int*)(ws + WS_PIDX),
                       (int*)(ws + WS_IDX), out + O_IDX, ws + WS_COUNTS);
    hipLaunchKernelGGL(k_quant, dim3(8192), dim3(256), 0, stream,
                       x, E, ws + WS_XR, (const int*)(ws + WS_IDX),
                       out + O_Q, ws + WS_DW, ws + WS_SCAL);
    hipLaunchKernelGGL(k_ema, dim3(1), dim3(1024), 0, stream,
                       ecs, ws + WS_COUNTS, out + O_CS, ws + WS_CS);
    hipLaunchKernelGGL(k_emb, dim3(256), dim3(256), 0, stream,
                       emaw, ws + WS_DW, ws + WS_CS, ws + WS_COUNTS,
                       out + O_EW, out + O_EMB, ws + WS_ESUM, ws + WS_SCAL);
    hipLaunchKernelGGL(k_final, dim3(1), dim3(1024), 0, stream,
                       ws + WS_COUNTS, ws + WS_SCAL, ws + WS_XRSUM,
                       ws + WS_ESUM, out);
}

// Round 2
// 231.108 us; speedup vs baseline: 1.1544x; 1.1544x over previous
//
#include <hip/hip_runtime.h>
#include <math.h>

#define NTOK 32768
#define KCB  1024
#define DIM  64

// ---- workspace layout (float offsets) ----
#define WS_XR      0                       // [NTOK*64] rotated vectors
#define WS_ENORM   2097152                 // [1024] ||e_k||^2
#define WS_COUNTS  (WS_ENORM + 1024)       // [1024] float counts
#define WS_CS      (WS_COUNTS + 1024)      // [1024] smoothed cluster size
#define WS_XRSUM   (WS_CS + 1024)          // [64]   sum_n xr[n][d]
#define WS_ESUM    (WS_XRSUM + 64)         // [64]   sum_k c_k*emb[k][d]
#define WS_SCAL    (WS_ESUM + 64)          // [16]: 0=sq_sum 1=xrnorm_sum 2=c*||emb||^2
#define WS_PMIN    (WS_SCAL + 16)          // [2*NTOK] partial min per k-half
#define WS_PIDX    (WS_PMIN + 65536)       // [2*NTOK] (int)
#define WS_IDX     (WS_PIDX + 65536)       // [NTOK]   (int)
// dead-region aliases (after k_merge, pmin/pidx are free):
#define WS_SORT    WS_PMIN                 // [NTOK] (int) code-sorted token ids
#define WS_OFF     WS_PIDX                 // [1024] (int) segment offsets
#define WS_CUR     (WS_PIDX + 1024)        // [1024] (int) scatter cursors

// ---- output layout (float offsets) ----
#define O_Q    0
#define O_CB   2097152
#define O_CM   2097153
#define O_DV   2097154
#define O_PP   2097155
#define O_IDX  2097156
#define O_CS   2129924
#define O_EW   2130948
#define O_EMB  2196484

// ---------------------------------------------------------------------------
// 1) rotate: xr = xf @ H, plus xr_sum[d] and scal[1] = sum ||xr||^2
__global__ __launch_bounds__(256) void k_rotate(const float* __restrict__ x,
    const float* __restrict__ rot, float* __restrict__ xr,
    float* __restrict__ xr_sum, float* __restrict__ scal)
{
    __shared__ float4 Hs[1024];
    __shared__ float  xs[64];
    __shared__ float  wred[4];
    int tid = threadIdx.x;
    const float4* rot4 = (const float4*)rot;
    for (int i = tid; i < 1024; i += 256) Hs[i] = rot4[i];
    if (tid < 64) xs[tid] = 0.f;
    __syncthreads();

    int n = blockIdx.x * 256 + tid;
    const float* xp = x + ((size_t)(n >> 10) << 16) + (n & 1023);
    float acc[64];
    #pragma unroll
    for (int d = 0; d < 64; ++d) acc[d] = 0.f;
    for (int j = 0; j < 64; ++j) {
        float xv = xp[(size_t)j << 10];
        #pragma unroll
        for (int q = 0; q < 16; ++q) {
            float4 h = Hs[(j << 4) + q];
            acc[4*q+0] = fmaf(xv, h.x, acc[4*q+0]);
            acc[4*q+1] = fmaf(xv, h.y, acc[4*q+1]);
            acc[4*q+2] = fmaf(xv, h.z, acc[4*q+2]);
            acc[4*q+3] = fmaf(xv, h.w, acc[4*q+3]);
        }
    }
    float4* xro = (float4*)(xr + ((size_t)n << 6));
    float nrm = 0.f;
    #pragma unroll
    for (int q = 0; q < 16; ++q) {
        float4 v = make_float4(acc[4*q], acc[4*q+1], acc[4*q+2], acc[4*q+3]);
        xro[q] = v;
        nrm += v.x*v.x + v.y*v.y + v.z*v.z + v.w*v.w;
    }
    #pragma unroll
    for (int d = 0; d < 64; ++d) {
        float v = acc[d];
        #pragma unroll
        for (int m = 32; m >= 1; m >>= 1) v += __shfl_xor(v, m);
        if ((tid & 63) == 0) atomicAdd(&xs[d], v);
    }
    #pragma unroll
    for (int m = 32; m >= 1; m >>= 1) nrm += __shfl_xor(nrm, m);
    if ((tid & 63) == 0) wred[tid >> 6] = nrm;
    __syncthreads();
    if (tid < 64) atomicAdd(&xr_sum[tid], xs[tid]);
    if (tid == 0) atomicAdd(&scal[1], wred[0] + wred[1] + wred[2] + wred[3]);
}

// ---------------------------------------------------------------------------
// 2) codebook norms
__global__ __launch_bounds__(256) void k_enorm(const float* __restrict__ E,
                                               float* __restrict__ enorm)
{
    int k = blockIdx.x * 256 + threadIdx.x;
    const float4* e4 = (const float4*)(E + ((size_t)k << 6));
    float s = 0.f;
    #pragma unroll
    for (int q = 0; q < 16; ++q) {
        float4 v = e4[q];
        s += v.x*v.x + v.y*v.y + v.z*v.z + v.w*v.w;
    }
    enorm[k] = s;
}

// ---------------------------------------------------------------------------
// 3) fused distance GEMM + argmin (f32 VALU; argmin is precision-critical)
#define LDT 132
__global__ __launch_bounds__(256) void k_argmin(const float* __restrict__ xr,
    const float* __restrict__ E, const float* __restrict__ enorm,
    float* __restrict__ pmin, int* __restrict__ pidx)
{
    __shared__ float xs[64 * LDT];
    __shared__ float es[64 * LDT];
    int tid = threadIdx.x;
    int tx = tid & 15, ty = tid >> 4;
    int nb = blockIdx.x >> 1;
    int kh = blockIdx.x & 1;
    int n0 = nb << 7;

    {
        const float4* src = (const float4*)(xr + ((size_t)n0 << 6));
        #pragma unroll
        for (int it = 0; it < 8; ++it) {
            int q = tid + (it << 8);
            int row = q >> 4, d4 = (q & 15) << 2;
            float4 v = src[q];
            xs[(d4+0)*LDT + row] = v.x;
            xs[(d4+1)*LDT + row] = v.y;
            xs[(d4+2)*LDT + row] = v.z;
            xs[(d4+3)*LDT + row] = v.w;
        }
    }

    float best[8]; int bidx[8];
    #pragma unroll
    for (int i = 0; i < 8; ++i) { best[i] = 3.4e38f; bidx[i] = 0; }

    for (int kc = 0; kc < 4; ++kc) {
        int kbase = (kh << 9) + (kc << 7);
        __syncthreads();
        {
            const float4* src = (const float4*)(E + ((size_t)kbase << 6));
            #pragma unroll
            for (int it = 0; it < 8; ++it) {
                int q = tid + (it << 8);
                int row = q >> 4, d4 = (q & 15) << 2;
                float4 v = src[q];
                es[(d4+0)*LDT + row] = v.x;
                es[(d4+1)*LDT + row] = v.y;
                es[(d4+2)*LDT + row] = v.z;
                es[(d4+3)*LDT + row] = v.w;
            }
        }
        __syncthreads();

        float acc[8][8];
        #pragma unroll
        for (int i = 0; i < 8; ++i)
            #pragma unroll
            for (int j = 0; j < 8; ++j) acc[i][j] = 0.f;

        int i0 = ty << 3, j0 = tx << 3;
        #pragma unroll 8
        for (int d = 0; d < 64; ++d) {
            const float* xa = &xs[d * LDT + i0];
            const float* eb = &es[d * LDT + j0];
            float4 a0 = *(const float4*)xa;
            float4 a1 = *(const float4*)(xa + 4);
            float4 b0 = *(const float4*)eb;
            float4 b1 = *(const float4*)(eb + 4);
            float a[8] = {a0.x,a0.y,a0.z,a0.w,a1.x,a1.y,a1.z,a1.w};
            float b[8] = {b0.x,b0.y,b0.z,b0.w,b1.x,b1.y,b1.z,b1.w};
            #pragma unroll
            for (int i = 0; i < 8; ++i)
                #pragma unroll
                for (int j = 0; j < 8; ++j)
                    acc[i][j] = fmaf(a[i], b[j], acc[i][j]);
        }

        #pragma unroll
        for (int j = 0; j < 8; ++j) {
            int k = kbase + j0 + j;
            float en = enorm[k];
            #pragma unroll
            for (int i = 0; i < 8; ++i) {
                float s = fmaf(-2.f, acc[i][j], en);
                if (s < best[i]) { best[i] = s; bidx[i] = k; }
            }
        }
    }

    #pragma unroll
    for (int i = 0; i < 8; ++i) {
        float v = best[i]; int id = bidx[i];
        #pragma unroll
        for (int m = 8; m >= 1; m >>= 1) {
            float v2 = __shfl_xor(v, m);
            int id2 = __shfl_xor(id, m);
            if (v2 < v || (v2 == v && id2 < id)) { v = v2; id = id2; }
        }
        if (tx == 0) {
            int r = n0 + (ty << 3) + i;
            pmin[(kh << 15) + r] = v;
            pidx[(kh << 15) + r] = id;
        }
    }
}

// ---------------------------------------------------------------------------
// 4) merge k-halves, emit idx (ws + out), float counts
__global__ __launch_bounds__(256) void k_merge(const float* __restrict__ pmin,
    const int* __restrict__ pidx, int* __restrict__ idxw,
    float* __restrict__ out_idx, float* __restrict__ counts)
{
    int n = blockIdx.x * 256 + threadIdx.x;
    float v0 = pmin[n];          int i0 = pidx[n];
    float v1 = pmin[32768 + n];  int i1 = pidx[32768 + n];
    int k = (v1 < v0 || (v1 == v0 && i1 < i0)) ? i1 : i0;
    idxw[n] = k;
    out_idx[n] = (float)k;
    atomicAdd(&counts[k], 1.0f);
}

// ---------------------------------------------------------------------------
// 5) EMA cluster size + Laplace smoothing + exclusive prefix scan of counts
__global__ __launch_bounds__(1024) void k_ema_scan(const float* __restrict__ ecs,
    const float* __restrict__ counts, float* __restrict__ out_cs,
    float* __restrict__ csw, int* __restrict__ off, int* __restrict__ cur)
{
    int k = threadIdx.x;
    float c = counts[k];
    float cs = ecs[k] * 0.99f + 0.01f * c;
    float v = cs;
    #pragma unroll
    for (int m = 32; m >= 1; m >>= 1) v += __shfl_xor(v, m);
    __shared__ float wr[16];
    __shared__ float ns;
    if ((k & 63) == 0) wr[k >> 6] = v;
    __syncthreads();
    if (k == 0) {
        float s = 0.f;
        for (int i = 0; i < 16; ++i) s += wr[i];
        ns = s;
    }
    // prefix scan of int counts (Hillis-Steele in LDS)
    __shared__ int sc[1024];
    int ci = (int)c;
    sc[k] = ci;
    __syncthreads();
    for (int s = 1; s < 1024; s <<= 1) {
        int add = (k >= s) ? sc[k - s] : 0;
        __syncthreads();
        sc[k] += add;
        __syncthreads();
    }
    int offk = sc[k] - ci;   // exclusive
    off[k] = offk;
    cur[k] = offk;

    float nn = ns;
    float csf = (cs + 1e-5f) / (nn + 1024.f * 1e-5f) * nn;
    out_cs[k] = csf;
    csw[k] = csf;
}

// ---------------------------------------------------------------------------
// 6) counting-sort scatter: token n -> sorted position within its code segment
__global__ __launch_bounds__(256) void k_scatter(const int* __restrict__ idxw,
    int* __restrict__ cur, int* __restrict__ sorted)
{
    int n = blockIdx.x * 256 + threadIdx.x;
    int k = idxw[n];
    int pos = atomicAdd(&cur[k], 1);
    sorted[pos] = n;
}

// ---------------------------------------------------------------------------
// 7) quant output (float4 streaming) + squared-error sum
__global__ __launch_bounds__(256) void k_quant(const float* __restrict__ x,
    const float* __restrict__ E, const int* __restrict__ idxw,
    float* __restrict__ outq, float* __restrict__ scal)
{
    int q = blockIdx.x * 256 + threadIdx.x;   // [0, 524288)
    int n = q >> 4, d4 = q & 15;
    int k = idxw[n];
    float4 xv = ((const float4*)x)[q];
    float4 ev = ((const float4*)E)[(k << 4) + d4];
    float dx = ev.x - xv.x, dy = ev.y - xv.y, dz = ev.z - xv.z, dw_ = ev.w - xv.w;
    float4 o = make_float4(xv.x + dx, xv.y + dy, xv.z + dz, xv.w + dw_);
    ((float4*)outq)[q] = o;
    float sq = dx*dx + dy*dy + dz*dz + dw_*dw_;
    #pragma unroll
    for (int m = 32; m >= 1; m >>= 1) sq += __shfl_xor(sq, m);
    __shared__ float wr[4];
    if ((threadIdx.x & 63) == 0) wr[threadIdx.x >> 6] = sq;
    __syncthreads();
    if (threadIdx.x == 0) atomicAdd(&scal[0], wr[0] + wr[1] + wr[2] + wr[3]);
}

// ---------------------------------------------------------------------------
// 8) per-code segmented reduction: dw (in regs) -> new_ema_w, new_embedding,
//    diversity partials. Block = code, 128 threads = 2 waves split the segment.
__global__ __launch_bounds__(128) void k_dwemb(const float* __restrict__ xr,
    const int* __restrict__ sorted, const int* __restrict__ off,
    const float* __restrict__ counts, const float* __restrict__ csw,
    const float* __restrict__ emaw, float* __restrict__ out_ew,
    float* __restrict__ out_emb, float* __restrict__ e_sum,
    float* __restrict__ scal)
{
    __shared__ float part[64];
    int k = blockIdx.x;
    int tid = threadIdx.x;
    int wave = tid >> 6, d = tid & 63;
    int a = off[k];
    int cnt = (int)counts[k];
    int end = a + cnt;

    float sum = 0.f;
    for (int t = a + wave; t < end; t += 2) {
        int tok = sorted[t];
        sum += xr[((size_t)tok << 6) + d];
    }
    if (wave == 1) part[d] = sum;
    __syncthreads();
    if (wave == 0) {
        float dw = sum + part[d];
        int i = (k << 6) + d;
        float nw = emaw[i] * 0.99f + 0.01f * dw;
        out_ew[i] = nw;
        float emb = nw / csw[k];
        out_emb[i] = emb;
        float c = (float)cnt;
        atomicAdd(&e_sum[d], c * emb);
        float t2 = c * emb * emb;
        #pragma unroll
        for (int m = 32; m >= 1; m >>= 1) t2 += __shfl_xor(t2, m);
        if (d == 0) atomicAdd(&scal[2], t2);
    }
}

// ---------------------------------------------------------------------------
// 9) finalize scalars
__global__ __launch_bounds__(1024) void k_final(const float* __restrict__ counts,
    const float* __restrict__ scal, const float* __restrict__ xr_sum,
    const float* __restrict__ e_sum, float* __restrict__ out)
{
    int tid = threadIdx.x;
    float a = counts[tid] * (1.f / 32768.f);
    float t = a * logf(a + 1e-10f);
    float dc = (tid < 64) ? e_sum[tid] * xr_sum[tid] : 0.f;
    #pragma unroll
    for (int m = 32; m >= 1; m >>= 1) { t += __shfl_xor(t, m); dc += __shfl_xor(dc, m); }
    __shared__ float wt[16], wd[16];
    if ((tid & 63) == 0) { wt[tid >> 6] = t; wd[tid >> 6] = dc; }
    __syncthreads();
    if (tid == 0) {
        float S = 0.f, Dt = 0.f;
        for (int i = 0; i < 16; ++i) { S += wt[i]; Dt += wd[i]; }
        float cb = scal[0] * (1.f / 2097152.f);
        out[O_CB] = cb;
        out[O_CM] = 0.25f * cb;
        float inv = 1.f / 32768.f;
        out[O_DV] = scal[2] * inv + scal[1] * inv - 2.f * (Dt * inv * inv);
        out[O_PP] = expf(-S);
    }
}

// ---------------------------------------------------------------------------
extern "C" void kernel_launch(void* const* d_in, const int* in_sizes, int n_in,
                              void* d_out, int out_size, void* d_ws, size_t ws_size,
                              hipStream_t stream)
{
    const float* x    = (const float*)d_in[0];
    const float* E    = (const float*)d_in[1];
    const float* rot  = (const float*)d_in[2];
    const float* emaw = (const float*)d_in[3];
    const float* ecs  = (const float*)d_in[4];
    float* out = (float*)d_out;
    float* ws  = (float*)d_ws;

    // zero accumulators: counts, cs, xr_sum, e_sum, scal (contiguous, 8.8 KB)
    hipMemsetAsync((void*)(ws + WS_COUNTS), 0,
                   (size_t)(WS_PMIN - WS_COUNTS) * sizeof(float), stream);

    hipLaunchKernelGGL(k_rotate, dim3(128), dim3(256), 0, stream,
                       x, rot, ws + WS_XR, ws + WS_XRSUM, ws + WS_SCAL);
    hipLaunchKernelGGL(k_enorm, dim3(4), dim3(256), 0, stream,
                       E, ws + WS_ENORM);
    hipLaunchKernelGGL(k_argmin, dim3(512), dim3(256), 0, stream,
                       ws + WS_XR, E, ws + WS_ENORM,
                       ws + WS_PMIN, (int*)(ws + WS_PIDX));
    hipLaunchKernelGGL(k_merge, dim3(128), dim3(256), 0, stream,
                       ws + WS_PMIN, (const int*)(ws + WS_PIDX),
                       (int*)(ws + WS_IDX), out + O_IDX, ws + WS_COUNTS);
    // pmin/pidx dead from here; aliased as sorted/off/cur
    hipLaunchKernelGGL(k_ema_scan, dim3(1), dim3(1024), 0, stream,
                       ecs, ws + WS_COUNTS, out + O_CS, ws + WS_CS,
                       (int*)(ws + WS_OFF), (int*)(ws + WS_CUR));
    hipLaunchKernelGGL(k_scatter, dim3(128), dim3(256), 0, stream,
                       (const int*)(ws + WS_IDX), (int*)(ws + WS_CUR),
                       (int*)(ws + WS_SORT));
    hipLaunchKernelGGL(k_quant, dim3(2048), dim3(256), 0, stream,
                       x, E, (const int*)(ws + WS_IDX), out + O_Q, ws + WS_SCAL);
    hipLaunchKernelGGL(k_dwemb, dim3(1024), dim3(128), 0, stream,
                       ws + WS_XR, (const int*)(ws + WS_SORT),
                       (const int*)(ws + WS_OFF), ws + WS_COUNTS, ws + WS_CS,
                       emaw, out + O_EW, out + O_EMB, ws + WS_ESUM, ws + WS_SCAL);
    hipLaunchKernelGGL(k_final, dim3(1), dim3(1024), 0, stream,
                       ws + WS_COUNTS, ws + WS_SCAL, ws + WS_XRSUM,
                       ws + WS_ESUM, out);
}

// Round 3
// 156.780 us; speedup vs baseline: 1.7017x; 1.4741x over previous
//
#include <hip/hip_runtime.h>
#include <math.h>

#define NTOK 32768
#define KCB  1024
#define DIM  64

// ---- workspace layout (float offsets) ----
#define WS_XR      0                       // [NTOK*64] rotated vectors
#define WS_ENORM   2097152                 // [1024] ||e_k||^2
#define WS_COUNTS  (WS_ENORM + 1024)       // [1024] float counts
#define WS_CS      (WS_COUNTS + 1024)      // [1024] smoothed cluster size
#define WS_XRSUM   (WS_CS + 1024)          // [64]   sum_n xr[n][d]
#define WS_ESUM    (WS_XRSUM + 64)         // [64]   sum_k c_k*emb[k][d]
#define WS_SCAL    (WS_ESUM + 64)          // [16]: 0=sq_sum 1=xrnorm_sum 2=c*||emb||^2
#define WS_PMIN    (WS_SCAL + 16)          // [2*NTOK] partial min per k-half
#define WS_PIDX    (WS_PMIN + 65536)       // [2*NTOK] (int)
#define WS_IDX     (WS_PIDX + 65536)       // [NTOK]   (int)
// dead-region aliases (after merge, pmin/pidx are free):
#define WS_SORT    WS_PMIN                 // [NTOK] (int) code-sorted token ids
#define WS_OFF     WS_PIDX                 // [1024] (int) segment offsets
#define WS_CUR     (WS_PIDX + 1024)        // [1024] (int) scatter cursors

// ---- output layout (float offsets) ----
#define O_Q    0
#define O_CB   2097152
#define O_CM   2097153
#define O_DV   2097154
#define O_PP   2097155
#define O_IDX  2097156
#define O_CS   2129924
#define O_EW   2130948
#define O_EMB  2196484

// ---------------------------------------------------------------------------
// 1) rotate via cross-lane FWHT (rotation matrix IS the Sylvester Hadamard).
//    Lane = dim, float4 components = 4 consecutive tokens. 6 butterfly stages
//    via __shfl_xor. Also computes xr_sum[d] and scal[1]=sum||xr||^2.
//    Blocks >= 512 compute codebook norms instead (fused k_enorm).
__global__ __launch_bounds__(256) void k_rotate_enorm(const float* __restrict__ x,
    const float* __restrict__ E, float* __restrict__ xr, float* __restrict__ enorm,
    float* __restrict__ xr_sum, float* __restrict__ scal)
{
    int tid = threadIdx.x;
    if (blockIdx.x >= 512) {   // enorm blocks
        int k = ((int)blockIdx.x - 512) * 256 + tid;
        const float4* e4 = (const float4*)(E + ((size_t)k << 6));
        float s = 0.f;
        #pragma unroll
        for (int q = 0; q < 16; ++q) {
            float4 v = e4[q];
            s += v.x*v.x + v.y*v.y + v.z*v.z + v.w*v.w;
        }
        enorm[k] = s;
        return;
    }
    __shared__ float xs[4][64];
    __shared__ float wred[4];
    int lane = tid & 63, w = tid >> 6;
    int g = blockIdx.x * 4 + w;            // wave id 0..2047
    float dsum = 0.f, nrm = 0.f;
    #pragma unroll
    for (int i = 0; i < 4; ++i) {
        int t0 = g * 16 + i * 4;           // 4 tokens, never crosses b-plane
        const float* src = x + ((size_t)(t0 >> 10) << 16) + lane * 1024 + (t0 & 1023);
        float4 v = *(const float4*)src;
        #pragma unroll
        for (int s = 1; s <= 32; s <<= 1) {
            float sgn = (lane & s) ? -1.f : 1.f;
            float ox = __shfl_xor(v.x, s);
            float oy = __shfl_xor(v.y, s);
            float oz = __shfl_xor(v.z, s);
            float ow = __shfl_xor(v.w, s);
            v.x = fmaf(sgn, v.x, ox);
            v.y = fmaf(sgn, v.y, oy);
            v.z = fmaf(sgn, v.z, oz);
            v.w = fmaf(sgn, v.w, ow);
        }
        float* dst = xr + ((size_t)t0 << 6) + lane;
        dst[0]   = v.x;
        dst[64]  = v.y;
        dst[128] = v.z;
        dst[192] = v.w;
        dsum += v.x + v.y + v.z + v.w;
        nrm  += v.x*v.x + v.y*v.y + v.z*v.z + v.w*v.w;
    }
    xs[w][lane] = dsum;
    #pragma unroll
    for (int m = 32; m >= 1; m >>= 1) nrm += __shfl_xor(nrm, m);
    if (lane == 0) wred[w] = nrm;
    __syncthreads();
    if (tid < 64) atomicAdd(&xr_sum[tid], xs[0][tid] + xs[1][tid] + xs[2][tid] + xs[3][tid]);
    if (tid == 0) atomicAdd(&scal[1], wred[0] + wred[1] + wred[2] + wred[3]);
}

// ---------------------------------------------------------------------------
// 2) fused distance GEMM + argmin. Block = 64 tokens x 512 codes (4 chunks of
//    128). 256 threads = 16tx x 16ty; per-thread 4 tokens x (4+4) codes.
//    LDS 51.2KB -> 3 blocks/CU. Split code columns (tx*4, 64+tx*4) -> 2-way
//    max bank aliasing on es reads; xs reads broadcast.
#define XS_LD 68
#define ES_LD 132
__global__ __launch_bounds__(256) void k_argmin(const float* __restrict__ xr,
    const float* __restrict__ E, const float* __restrict__ enorm,
    float* __restrict__ pmin, int* __restrict__ pidx)
{
    __shared__ float xs[64 * XS_LD];
    __shared__ float es[64 * ES_LD];
    int tid = threadIdx.x;
    int tx = tid & 15, ty = tid >> 4;
    int nb = blockIdx.x >> 1, kh = blockIdx.x & 1;
    int n0 = nb << 6;

    {   // stage xr tile transposed: coalesced f4 loads
        const float4* src = (const float4*)(xr + ((size_t)n0 << 6));
        #pragma unroll
        for (int it = 0; it < 4; ++it) {
            int q = (it << 8) + tid;           // f4 index in 64x16 tile
            int r = q >> 4, c4 = (q & 15) << 2;
            float4 v = src[q];
            xs[(c4+0)*XS_LD + r] = v.x;
            xs[(c4+1)*XS_LD + r] = v.y;
            xs[(c4+2)*XS_LD + r] = v.z;
            xs[(c4+3)*XS_LD + r] = v.w;
        }
    }

    float best[4]; int bidx[4];
    #pragma unroll
    for (int i = 0; i < 4; ++i) { best[i] = 3.4e38f; bidx[i] = 0; }

    for (int kc = 0; kc < 4; ++kc) {
        int kbase = (kh << 9) + (kc << 7);
        __syncthreads();   // previous chunk's reads done (also covers xs staging)
        {
            const float4* src = (const float4*)(E + ((size_t)kbase << 6));
            #pragma unroll
            for (int it = 0; it < 8; ++it) {
                int q = (it << 8) + tid;       // f4 index in 128x16 tile
                int r = q >> 4, c4 = (q & 15) << 2;
                float4 v = src[q];
                es[(c4+0)*ES_LD + r] = v.x;
                es[(c4+1)*ES_LD + r] = v.y;
                es[(c4+2)*ES_LD + r] = v.z;
                es[(c4+3)*ES_LD + r] = v.w;
            }
        }
        __syncthreads();

        float acc[4][8];
        #pragma unroll
        for (int i = 0; i < 4; ++i)
            #pragma unroll
            for (int j = 0; j < 8; ++j) acc[i][j] = 0.f;

        const float* xp = xs + (ty << 2);
        const float* ep = es + (tx << 2);
        #pragma unroll 4
        for (int d = 0; d < 64; ++d) {
            float4 av = *(const float4*)(xp + d * XS_LD);
            float4 b0 = *(const float4*)(ep + d * ES_LD);
            float4 b1 = *(const float4*)(ep + d * ES_LD + 64);
            float a[4] = {av.x, av.y, av.z, av.w};
            float b[8] = {b0.x, b0.y, b0.z, b0.w, b1.x, b1.y, b1.z, b1.w};
            #pragma unroll
            for (int i = 0; i < 4; ++i)
                #pragma unroll
                for (int j = 0; j < 8; ++j)
                    acc[i][j] = fmaf(a[i], b[j], acc[i][j]);
        }

        #pragma unroll
        for (int j = 0; j < 8; ++j) {
            int k = kbase + ((j < 4) ? ((tx << 2) + j) : (64 + (tx << 2) + j - 4));
            float en = enorm[k];
            #pragma unroll
            for (int i = 0; i < 4; ++i) {
                float s = fmaf(-2.f, acc[i][j], en);
                if (s < best[i]) { best[i] = s; bidx[i] = k; }
            }
        }
    }

    // reduce across the 16 tx lanes (contiguous within wave)
    #pragma unroll
    for (int i = 0; i < 4; ++i) {
        float v = best[i]; int id = bidx[i];
        #pragma unroll
        for (int m = 8; m >= 1; m >>= 1) {
            float v2 = __shfl_xor(v, m);
            int id2 = __shfl_xor(id, m);
            if (v2 < v || (v2 == v && id2 < id)) { v = v2; id = id2; }
        }
        if (tx == 0) {
            int r = n0 + (ty << 2) + i;
            pmin[(kh << 15) + r] = v;
            pidx[(kh << 15) + r] = id;
        }
    }
}

// ---------------------------------------------------------------------------
// 3) merge k-halves + counts + FUSED quant output & sq-error (block owns a
//    contiguous 256-token span -> contiguous 16K-float quant/x region).
__global__ __launch_bounds__(256) void k_mergequant(const float* __restrict__ pmin,
    const int* __restrict__ pidx, const float* __restrict__ x,
    const float* __restrict__ E, int* __restrict__ idxw,
    float* __restrict__ out_idx, float* __restrict__ counts,
    float* __restrict__ outq, float* __restrict__ scal)
{
    __shared__ int lidx[256];
    __shared__ float wr[4];
    int tid = threadIdx.x;
    int n = blockIdx.x * 256 + tid;
    float v0 = pmin[n];          int i0 = pidx[n];
    float v1 = pmin[32768 + n];  int i1 = pidx[32768 + n];
    int k = (v1 < v0 || (v1 == v0 && i1 < i0)) ? i1 : i0;
    idxw[n] = k;
    out_idx[n] = (float)k;
    atomicAdd(&counts[k], 1.0f);
    lidx[tid] = k;
    __syncthreads();

    int f40 = blockIdx.x * 4096;          // 256 tokens * 16 f4
    float sq = 0.f;
    #pragma unroll 4
    for (int it = 0; it < 16; ++it) {
        int q = (it << 8) + tid;          // local f4 index
        int kk = lidx[q >> 4];
        int d4 = q & 15;
        float4 xv = ((const float4*)x)[f40 + q];
        float4 ev = ((const float4*)E)[(kk << 4) + d4];
        float dx = ev.x - xv.x, dy = ev.y - xv.y, dz = ev.z - xv.z, dw_ = ev.w - xv.w;
        ((float4*)outq)[f40 + q] = make_float4(xv.x + dx, xv.y + dy, xv.z + dz, xv.w + dw_);
        sq += dx*dx + dy*dy + dz*dz + dw_*dw_;
    }
    #pragma unroll
    for (int m = 32; m >= 1; m >>= 1) sq += __shfl_xor(sq, m);
    if ((tid & 63) == 0) wr[tid >> 6] = sq;
    __syncthreads();
    if (tid == 0) atomicAdd(&scal[0], wr[0] + wr[1] + wr[2] + wr[3]);
}

// ---------------------------------------------------------------------------
// 4) EMA cluster size + Laplace smoothing + exclusive prefix scan of counts
__global__ __launch_bounds__(1024) void k_ema_scan(const float* __restrict__ ecs,
    const float* __restrict__ counts, float* __restrict__ out_cs,
    float* __restrict__ csw, int* __restrict__ off, int* __restrict__ cur)
{
    int k = threadIdx.x;
    float c = counts[k];
    float cs = ecs[k] * 0.99f + 0.01f * c;
    float v = cs;
    #pragma unroll
    for (int m = 32; m >= 1; m >>= 1) v += __shfl_xor(v, m);
    __shared__ float wr[16];
    __shared__ float ns;
    if ((k & 63) == 0) wr[k >> 6] = v;
    __syncthreads();
    if (k == 0) {
        float s = 0.f;
        for (int i = 0; i < 16; ++i) s += wr[i];
        ns = s;
    }
    __shared__ int sc[1024];
    int ci = (int)c;
    sc[k] = ci;
    __syncthreads();
    for (int s = 1; s < 1024; s <<= 1) {
        int add = (k >= s) ? sc[k - s] : 0;
        __syncthreads();
        sc[k] += add;
        __syncthreads();
    }
    int offk = sc[k] - ci;
    off[k] = offk;
    cur[k] = offk;

    float nn = ns;
    float csf = (cs + 1e-5f) / (nn + 1024.f * 1e-5f) * nn;
    out_cs[k] = csf;
    csw[k] = csf;
}

// ---------------------------------------------------------------------------
// 5) counting-sort scatter
__global__ __launch_bounds__(256) void k_scatter(const int* __restrict__ idxw,
    int* __restrict__ cur, int* __restrict__ sorted)
{
    int n = blockIdx.x * 256 + threadIdx.x;
    int k = idxw[n];
    int pos = atomicAdd(&cur[k], 1);
    sorted[pos] = n;
}

// ---------------------------------------------------------------------------
// 6) per-code segmented reduction -> new_ema_w, new_embedding, diversity
//    partials. 256 threads = 4 waves stride the segment.
__global__ __launch_bounds__(256) void k_dwemb(const float* __restrict__ xr,
    const int* __restrict__ sorted, const int* __restrict__ off,
    const float* __restrict__ counts, const float* __restrict__ csw,
    const float* __restrict__ emaw, float* __restrict__ out_ew,
    float* __restrict__ out_emb, float* __restrict__ e_sum,
    float* __restrict__ scal)
{
    __shared__ float part[3][64];
    int k = blockIdx.x;
    int tid = threadIdx.x;
    int w = tid >> 6, d = tid & 63;
    int a = off[k];
    int cnt = (int)counts[k];
    int end = a + cnt;

    float sum = 0.f;
    for (int t = a + w; t < end; t += 4) {
        int tok = sorted[t];
        sum += xr[((size_t)tok << 6) + d];
    }
    if (w) part[w - 1][d] = sum;
    __syncthreads();
    if (w == 0) {
        float dw = sum + part[0][d] + part[1][d] + part[2][d];
        int i = (k << 6) + d;
        float nw = emaw[i] * 0.99f + 0.01f * dw;
        out_ew[i] = nw;
        float emb = nw / csw[k];
        out_emb[i] = emb;
        if (cnt > 0) {
            float c = (float)cnt;
            atomicAdd(&e_sum[d], c * emb);
            float t2 = c * emb * emb;
            #pragma unroll
            for (int m = 32; m >= 1; m >>= 1) t2 += __shfl_xor(t2, m);
            if (d == 0) atomicAdd(&scal[2], t2);
        }
    }
}

// ---------------------------------------------------------------------------
// 7) finalize scalars
__global__ __launch_bounds__(1024) void k_final(const float* __restrict__ counts,
    const float* __restrict__ scal, const float* __restrict__ xr_sum,
    const float* __restrict__ e_sum, float* __restrict__ out)
{
    int tid = threadIdx.x;
    float a = counts[tid] * (1.f / 32768.f);
    float t = a * logf(a + 1e-10f);
    float dc = (tid < 64) ? e_sum[tid] * xr_sum[tid] : 0.f;
    #pragma unroll
    for (int m = 32; m >= 1; m >>= 1) { t += __shfl_xor(t, m); dc += __shfl_xor(dc, m); }
    __shared__ float wt[16], wd[16];
    if ((tid & 63) == 0) { wt[tid >> 6] = t; wd[tid >> 6] = dc; }
    __syncthreads();
    if (tid == 0) {
        float S = 0.f, Dt = 0.f;
        for (int i = 0; i < 16; ++i) { S += wt[i]; Dt += wd[i]; }
        float cb = scal[0] * (1.f / 2097152.f);
        out[O_CB] = cb;
        out[O_CM] = 0.25f * cb;
        float inv = 1.f / 32768.f;
        out[O_DV] = scal[2] * inv + scal[1] * inv - 2.f * (Dt * inv * inv);
        out[O_PP] = expf(-S);
    }
}

// ---------------------------------------------------------------------------
extern "C" void kernel_launch(void* const* d_in, const int* in_sizes, int n_in,
                              void* d_out, int out_size, void* d_ws, size_t ws_size,
                              hipStream_t stream)
{
    const float* x    = (const float*)d_in[0];
    const float* E    = (const float*)d_in[1];
    const float* emaw = (const float*)d_in[3];
    const float* ecs  = (const float*)d_in[4];
    float* out = (float*)d_out;
    float* ws  = (float*)d_ws;

    // zero accumulators: counts, cs, xr_sum, e_sum, scal
    hipMemsetAsync((void*)(ws + WS_COUNTS), 0,
                   (size_t)(WS_PMIN - WS_COUNTS) * sizeof(float), stream);

    hipLaunchKernelGGL(k_rotate_enorm, dim3(516), dim3(256), 0, stream,
                       x, E, ws + WS_XR, ws + WS_ENORM, ws + WS_XRSUM, ws + WS_SCAL);
    hipLaunchKernelGGL(k_argmin, dim3(1024), dim3(256), 0, stream,
                       ws + WS_XR, E, ws + WS_ENORM,
                       ws + WS_PMIN, (int*)(ws + WS_PIDX));
    hipLaunchKernelGGL(k_mergequant, dim3(128), dim3(256), 0, stream,
                       ws + WS_PMIN, (const int*)(ws + WS_PIDX), x, E,
                       (int*)(ws + WS_IDX), out + O_IDX, ws + WS_COUNTS,
                       out + O_Q, ws + WS_SCAL);
    hipLaunchKernelGGL(k_ema_scan, dim3(1), dim3(1024), 0, stream,
                       ecs, ws + WS_COUNTS, out + O_CS, ws + WS_CS,
                       (int*)(ws + WS_OFF), (int*)(ws + WS_CUR));
    hipLaunchKernelGGL(k_scatter, dim3(128), dim3(256), 0, stream,
                       (const int*)(ws + WS_IDX), (int*)(ws + WS_CUR),
                       (int*)(ws + WS_SORT));
    hipLaunchKernelGGL(k_dwemb, dim3(1024), dim3(256), 0, stream,
                       ws + WS_XR, (const int*)(ws + WS_SORT),
                       (const int*)(ws + WS_OFF), ws + WS_COUNTS, ws + WS_CS,
                       emaw, out + O_EW, out + O_EMB, ws + WS_ESUM, ws + WS_SCAL);
    hipLaunchKernelGGL(k_final, dim3(1), dim3(1024), 0, stream,
                       ws + WS_COUNTS, ws + WS_SCAL, ws + WS_XRSUM,
                       ws + WS_ESUM, out);
}